// Round 16
// baseline (766.962 us; speedup 1.0000x reference)
//
#include <hip/hip_runtime.h>
#include <hip/hip_bf16.h>

typedef unsigned int u32;
typedef unsigned short u16;

#define DI __device__ __forceinline__

typedef __attribute__((ext_vector_type(8))) __bf16 bf16x8;
typedef __attribute__((ext_vector_type(4))) float f32x4;

// ---------- bf16 helpers (bf16 == fp32 high 16 bits; RNE on store) ----------
DI float b2f_u(u32 u){ return __uint_as_float(u << 16); }
DI u16 f2b_u(float f){
  u32 x = __float_as_uint(f);
  x += 0x7fffu + ((x >> 16) & 1u);
  return (u16)(x >> 16);
}
DI void ld8b(const u16* p, float* o){
  uint4 v = *reinterpret_cast<const uint4*>(p);
  o[0] = b2f_u(v.x & 0xffffu); o[1] = b2f_u(v.x >> 16);
  o[2] = b2f_u(v.y & 0xffffu); o[3] = b2f_u(v.y >> 16);
  o[4] = b2f_u(v.z & 0xffffu); o[5] = b2f_u(v.z >> 16);
  o[6] = b2f_u(v.w & 0xffffu); o[7] = b2f_u(v.w >> 16);
}
DI void st8b(u16* p, const float* i){
  uint4 v;
  v.x = (u32)f2b_u(i[0]) | ((u32)f2b_u(i[1]) << 16);
  v.y = (u32)f2b_u(i[2]) | ((u32)f2b_u(i[3]) << 16);
  v.z = (u32)f2b_u(i[4]) | ((u32)f2b_u(i[5]) << 16);
  v.w = (u32)f2b_u(i[6]) | ((u32)f2b_u(i[7]) << 16);
  *reinterpret_cast<uint4*>(p) = v;
}

// ---------- K_detect: is d_in fp32 (flag=1) or packed bf16 (flag=0)? ----------
__global__ void k_detect(const u32* __restrict__ xw, int* __restrict__ flag){
  __shared__ int cnt;
  int t = threadIdx.x;
  if (t == 0) cnt = 0;
  __syncthreads();
  int c = 0;
  for (int i = t; i < 2048; i += 256){
    u32 lo = xw[i] & 0xffffu;
    u32 e = (lo >> 7) & 0xffu;
    if (e < 100u || e > 140u) c++;
  }
  atomicAdd(&cnt, c);
  __syncthreads();
  if (t == 0) *flag = (cnt > 200) ? 1 : 0;
}

// ---------- K_prep: ALL weight/bias conversions in ONE launch ----------
__global__ void k_prep(
  const void* __restrict__ conv_w, const void* __restrict__ qkv1_w,
  const void* __restrict__ m1w1, const void* __restrict__ m1w2,
  const void* __restrict__ qkv2_w, const void* __restrict__ m2w1, const void* __restrict__ m2w2,
  const void* __restrict__ lwx, const void* __restrict__ lwh,
  const void* __restrict__ conv_b, const void* __restrict__ qkv1_b,
  const void* __restrict__ m1b1, const void* __restrict__ m1b2,
  const void* __restrict__ qkv2_b, const void* __restrict__ m2b1, const void* __restrict__ m2b2,
  const void* __restrict__ lbh,
  u16* __restrict__ wB_conv, u16* __restrict__ wB_qkv1, u16* __restrict__ wB_m1a,
  u16* __restrict__ wB_m1b, u16* __restrict__ wB_qkv2, u16* __restrict__ wB_m2a,
  u16* __restrict__ wB_m2b, u16* __restrict__ wBx, u16* __restrict__ wBh,
  float* __restrict__ bf_conv, float* __restrict__ bf_qkv1, float* __restrict__ bf_m1b1,
  float* __restrict__ bf_m1b2, float* __restrict__ bf_qkv2, float* __restrict__ bf_m2b1,
  float* __restrict__ bf_m2b2, float* __restrict__ bf_lbh,
  const int* __restrict__ flag){
  int bid = blockIdx.x, t = threadIdx.x;
  int fl = *flag;
  auto cvb = [&](const void* s, u16* d, int base, int n){
    int i = (bid - base)*256 + t;
    if (i < n) d[i] = fl ? f2b_u(((const float*)s)[i]) : ((const u16*)s)[i];
  };
  auto ldf = [&](const void* s, int i)->float{
    return fl ? ((const float*)s)[i] : b2f_u((u32)((const u16*)s)[i]);
  };
  if (bid < 256)       cvb(conv_w, wB_conv, 0,    65536);
  else if (bid < 448)  cvb(qkv1_w, wB_qkv1, 256,  49152);
  else if (bid < 704)  cvb(m1w1,   wB_m1a,  448,  65536);
  else if (bid < 960)  cvb(m1w2,   wB_m1b,  704,  65536);
  else if (bid < 1152) cvb(qkv2_w, wB_qkv2, 960,  49152);
  else if (bid < 1408) cvb(m2w1,   wB_m2a,  1152, 65536);
  else if (bid < 1664) cvb(m2w2,   wB_m2b,  1408, 65536);
  else if (bid < 1920) cvb(lwx,    wBx,     1664, 65536);
  else if (bid < 2176) cvb(lwh,    wBh,     1920, 65536);
  else {
    int i = (bid - 2176)*256 + t;
    if (i < 128)       bf_conv[i]        = ldf(conv_b, i);
    else if (i < 512)  bf_qkv1[i-128]    = ldf(qkv1_b, i-128);
    else if (i < 1024) bf_m1b1[i-512]    = ldf(m1b1,   i-512);
    else if (i < 1152) bf_m1b2[i-1024]   = ldf(m1b2,   i-1024);
    else if (i < 1536) bf_qkv2[i-1152]   = ldf(qkv2_b, i-1152);
    else if (i < 2048) bf_m2b1[i-1536]   = ldf(m2b1,   i-1536);
    else if (i < 2176) bf_m2b2[i-2048]   = ldf(m2b2,   i-2048);
    else if (i < 2688) bf_lbh[i-2176]    = ldf(lbh,    i-2176);
  }
}

// ---------- K1: conv 2x2 s2 + window partition via MFMA, strip-blocked ----------
__global__ __launch_bounds__(256) void k_conv(const void* __restrict__ x_raw,
                                              const u16* __restrict__ wB,
                                              const float* __restrict__ bias, u16* __restrict__ outA,
                                              const int* __restrict__ flag){
  __shared__ __align__(16) u16 pool[128*136];   // Aa [128][72] (first 18.4KB); Ys [128][136] overlay
  u16* Aa = pool;
  u16* Ys = pool;
  int t = threadIdx.x, bid = blockIdx.x;
  int xh = bid & 1, yg = (bid >> 1) & 15, b = bid >> 5;
  size_t slab = (size_t)b*2097152 + (size_t)(yg*8)*128 + (size_t)xh*64;
  int w = t >> 6, lane = t & 63, fr = lane & 15, fg = lane >> 4;
  f32x4 acc[2][8];
  #pragma unroll
  for (int j=0;j<8;j++){
    float bv = bias[j*16 + fr];
    acc[0][j] = {bv,bv,bv,bv};
    acc[1][j] = {bv,bv,bv,bv};
  }
  for (int ci0 = 0; ci0 < 128; ci0 += 16){
    if (ci0) __syncthreads();
    if (*flag){
      const float* xb = (const float*)x_raw + slab + (size_t)ci0*16384;
      #pragma unroll
      for (int i=0;i<4;i++){
        int idx = i*256 + t;            // 0..1023
        int row = idx >> 3, seg = idx & 7;   // row = cr*8+py (0..127), seg = 8-px group
        int cr = row >> 3, py = row & 7;
        const float* sp = xb + (size_t)cr*16384 + py*128 + seg*8;
        float4 v0 = *reinterpret_cast<const float4*>(sp);
        float4 v1 = *reinterpret_cast<const float4*>(sp + 4);
        int tok0 = seg*16 + (py>>1)*4;
        int k0 = cr*4 + (py&1)*2;
        *reinterpret_cast<u32*>(&Aa[(tok0+0)*72 + k0]) = (u32)f2b_u(v0.x) | ((u32)f2b_u(v0.y)<<16);
        *reinterpret_cast<u32*>(&Aa[(tok0+1)*72 + k0]) = (u32)f2b_u(v0.z) | ((u32)f2b_u(v0.w)<<16);
        *reinterpret_cast<u32*>(&Aa[(tok0+2)*72 + k0]) = (u32)f2b_u(v1.x) | ((u32)f2b_u(v1.y)<<16);
        *reinterpret_cast<u32*>(&Aa[(tok0+3)*72 + k0]) = (u32)f2b_u(v1.z) | ((u32)f2b_u(v1.w)<<16);
      }
    } else {
      const u16* xb = (const u16*)x_raw + slab + (size_t)ci0*16384;
      #pragma unroll
      for (int i=0;i<4;i++){
        int idx = i*256 + t;
        int row = idx >> 3, seg = idx & 7;
        int cr = row >> 3, py = row & 7;
        uint4 v = *reinterpret_cast<const uint4*>(xb + (size_t)cr*16384 + py*128 + seg*8);
        int tok0 = seg*16 + (py>>1)*4;
        int k0 = cr*4 + (py&1)*2;
        *reinterpret_cast<u32*>(&Aa[(tok0+0)*72 + k0]) = v.x;
        *reinterpret_cast<u32*>(&Aa[(tok0+1)*72 + k0]) = v.y;
        *reinterpret_cast<u32*>(&Aa[(tok0+2)*72 + k0]) = v.z;
        *reinterpret_cast<u32*>(&Aa[(tok0+3)*72 + k0]) = v.w;
      }
    }
    __syncthreads();
    bf16x8 a0[2], a1[2];
    #pragma unroll
    for (int kk=0;kk<2;kk++){
      a0[kk] = *reinterpret_cast<const bf16x8*>(&Aa[(w*16+fr)*72 + kk*32 + fg*8]);
      a1[kk] = *reinterpret_cast<const bf16x8*>(&Aa[((w+4)*16+fr)*72 + kk*32 + fg*8]);
    }
    #pragma unroll
    for (int j=0;j<8;j++){
      const u16* wp = wB + (size_t)(j*16+fr)*512 + ci0*4 + fg*8;
      bf16x8 b0 = *reinterpret_cast<const bf16x8*>(wp);
      bf16x8 b1 = *reinterpret_cast<const bf16x8*>(wp + 32);
      acc[0][j] = __builtin_amdgcn_mfma_f32_16x16x32_bf16(a0[0], b0, acc[0][j], 0, 0, 0);
      acc[0][j] = __builtin_amdgcn_mfma_f32_16x16x32_bf16(a0[1], b1, acc[0][j], 0, 0, 0);
      acc[1][j] = __builtin_amdgcn_mfma_f32_16x16x32_bf16(a1[0], b0, acc[1][j], 0, 0, 0);
      acc[1][j] = __builtin_amdgcn_mfma_f32_16x16x32_bf16(a1[1], b1, acc[1][j], 0, 0, 0);
    }
  }
  __syncthreads();
  #pragma unroll
  for (int tt=0;tt<2;tt++){
    int tokbase = (w + tt*4)*16;
    #pragma unroll
    for (int j=0;j<8;j++){
      #pragma unroll
      for (int r=0;r<4;r++)
        Ys[(tokbase + fg*4 + r)*136 + j*16 + fr] = f2b_u(acc[tt][j][r]);
    }
  }
  __syncthreads();
  {
    int tok = t >> 1, half = t & 1;
    int gl = yg*16 + xh*8 + (tok >> 4);
    int l = tok & 15;
    u16* dst = outA + ((size_t)(b*256 + gl)*16 + l)*128 + half*64;
    const u16* src = &Ys[tok*136 + half*64];
    #pragma unroll
    for (int q2=0;q2<8;q2++)
      *reinterpret_cast<uint4*>(dst + q2*8) = *reinterpret_cast<const uint4*>(src + q2*8);
  }
}

// ---------- K2: LocalMSA (L=16) + residual: bufA -> bufB (same layout) ----------
__global__ __launch_bounds__(256) void k_msa1(const u16* __restrict__ A, const u16* __restrict__ wB,
                                              const float* __restrict__ qbias, u16* __restrict__ B){
  __shared__ u16 Xs[16*136];        // bf16, row stride 272 B
  __shared__ float QKV[16*388];
  __shared__ float S[512];          // [h][l][m]
  int t = threadIdx.x, bid = blockIdx.x;
  {
    int l = t >> 4, c0 = (t & 15)*8;
    *reinterpret_cast<uint4*>(&Xs[l*136 + c0]) =
      *reinterpret_cast<const uint4*>(A + (size_t)bid*2048 + l*128 + c0);
  }
  __syncthreads();
  {
    int w = t >> 6, lane = t & 63, fr = lane & 15, fg = lane >> 4;
    bf16x8 a[4];
    #pragma unroll
    for (int k=0;k<4;k++) a[k] = *reinterpret_cast<const bf16x8*>(&Xs[fr*136 + k*32 + fg*8]);
    #pragma unroll
    for (int j=0;j<6;j++){
      int o = w*96 + j*16 + fr;          // 0..383
      float bv = qbias[o];
      f32x4 d = {bv,bv,bv,bv};
      const u16* wp = wB + (size_t)o*128 + fg*8;
      #pragma unroll
      for (int k=0;k<4;k++){
        bf16x8 b = *reinterpret_cast<const bf16x8*>(wp + k*32);
        d = __builtin_amdgcn_mfma_f32_16x16x32_bf16(a[k], b, d, 0, 0, 0);
      }
      #pragma unroll
      for (int r=0;r<4;r++) QKV[(fg*4+r)*388 + o] = d[r];
    }
  }
  __syncthreads();
  const float scale = 0.08838834764831845f;   // 1/sqrt(128)
  for (int e = t; e < 512; e += 256){
    int h = e >> 8, l = (e>>4)&15, m = e&15;
    const float* q = &QKV[l*388 + h*64];
    const float* kk = &QKV[m*388 + 128 + h*64];
    float s = 0.f;
    #pragma unroll
    for (int d=0; d<64; d++) s += q[d]*kk[d];
    S[(h*16+l)*16 + m] = s*scale;
  }
  __syncthreads();
  if (t < 32){
    float* row = &S[t*16];
    float mx = row[0];
    #pragma unroll
    for (int m=1;m<16;m++) mx = fmaxf(mx,row[m]);
    float sum = 0.f;
    #pragma unroll
    for (int m=0;m<16;m++){ float e = expf(row[m]-mx); row[m]=e; sum+=e; }
    float inv = 1.0f/sum;
    #pragma unroll
    for (int m=0;m<16;m++) row[m] *= inv;
  }
  __syncthreads();
  {
    int l = t >> 4, og = t & 15, o0 = og*8;
    int h = o0 >> 6;
    const float* p = &S[(h*16+l)*16];
    float out8[8];
    #pragma unroll
    for (int j=0;j<8;j++){
      int o = o0+j, d = o & 63;
      float s = 0.f;
      #pragma unroll
      for (int m=0;m<16;m++) s += p[m]*QKV[m*388 + 256 + h*64 + d];
      out8[j] = s + b2f_u((u32)Xs[l*136 + o]);
    }
    st8b(B + (size_t)bid*2048 + l*128 + o0, out8);
  }
}

// ---------- K3/K5: MLP (+residual) via MFMA, 32 tokens/block (2 tiles/wave). ----------
template<int MODE>
__global__ __launch_bounds__(256) void k_mlp(const u16* __restrict__ in,
    const u16* __restrict__ w1B, const float* __restrict__ b1,
    const u16* __restrict__ w2B, const float* __restrict__ b2,
    u16* __restrict__ out){
  __shared__ u16 Xs[32*136];        // bf16 input (also residual)
  __shared__ u16 Hs[32*520];        // bf16 hidden
  __shared__ u16 Ys[32*136];        // bf16 output staging
  int t = threadIdx.x, bid = blockIdx.x;
  {
    int l = t >> 3, c0 = (t & 7)*16;
    const u16* src = in + (size_t)bid*4096 + l*128 + c0;
    *reinterpret_cast<uint4*>(&Xs[l*136 + c0])     = *reinterpret_cast<const uint4*>(src);
    *reinterpret_cast<uint4*>(&Xs[l*136 + c0 + 8]) = *reinterpret_cast<const uint4*>(src + 8);
  }
  __syncthreads();
  int w = t >> 6, lane = t & 63, fr = lane & 15, fg = lane >> 4;

  // ---- GEMM1: H = gelu(X @ W1^T + b1); wave = 8 n-tiles x 2 tok-tiles ----
  {
    bf16x8 a0[4], a1[4];
    #pragma unroll
    for (int k=0;k<4;k++){
      a0[k] = *reinterpret_cast<const bf16x8*>(&Xs[fr*136 + k*32 + fg*8]);
      a1[k] = *reinterpret_cast<const bf16x8*>(&Xs[(16+fr)*136 + k*32 + fg*8]);
    }
    #pragma unroll
    for (int j=0;j<8;j++){
      int o = w*128 + j*16 + fr;        // 0..511
      float bv = b1[o];
      f32x4 d0 = {bv,bv,bv,bv}, d1 = {bv,bv,bv,bv};
      const u16* wp = w1B + (size_t)o*128 + fg*8;
      #pragma unroll
      for (int k=0;k<4;k++){
        bf16x8 b = *reinterpret_cast<const bf16x8*>(wp + k*32);
        d0 = __builtin_amdgcn_mfma_f32_16x16x32_bf16(a0[k], b, d0, 0, 0, 0);
        d1 = __builtin_amdgcn_mfma_f32_16x16x32_bf16(a1[k], b, d1, 0, 0, 0);
      }
      #pragma unroll
      for (int r=0;r<4;r++){
        float v0 = d0[r], v1 = d1[r];
        Hs[(fg*4+r)*520 + o]      = f2b_u(0.5f*v0*(1.0f + erff(v0*0.70710678118654752f)));
        Hs[(16+fg*4+r)*520 + o]   = f2b_u(0.5f*v1*(1.0f + erff(v1*0.70710678118654752f)));
      }
    }
  }
  __syncthreads();

  // ---- GEMM2: Y = H @ W2^T + b2 + X; wave = 2 n-tiles x 2 tok-tiles ----
  {
    int na = w*32 + fr, nb = na + 16;   // 0..127
    float ba = b2[na], bb = b2[nb];
    f32x4 d00 = {ba,ba,ba,ba}, d01 = {bb,bb,bb,bb};
    f32x4 d10 = {ba,ba,ba,ba}, d11 = {bb,bb,bb,bb};
    const u16* wpa = w2B + (size_t)na*512 + fg*8;
    const u16* wpb = w2B + (size_t)nb*512 + fg*8;
    #pragma unroll
    for (int k=0;k<16;k++){
      bf16x8 aa = *reinterpret_cast<const bf16x8*>(&Hs[fr*520 + k*32 + fg*8]);
      bf16x8 ab = *reinterpret_cast<const bf16x8*>(&Hs[(16+fr)*520 + k*32 + fg*8]);
      bf16x8 bA = *reinterpret_cast<const bf16x8*>(wpa + k*32);
      bf16x8 bB = *reinterpret_cast<const bf16x8*>(wpb + k*32);
      d00 = __builtin_amdgcn_mfma_f32_16x16x32_bf16(aa, bA, d00, 0, 0, 0);
      d01 = __builtin_amdgcn_mfma_f32_16x16x32_bf16(aa, bB, d01, 0, 0, 0);
      d10 = __builtin_amdgcn_mfma_f32_16x16x32_bf16(ab, bA, d10, 0, 0, 0);
      d11 = __builtin_amdgcn_mfma_f32_16x16x32_bf16(ab, bB, d11, 0, 0, 0);
    }
    #pragma unroll
    for (int r=0;r<4;r++){
      int ta = fg*4 + r, tb = 16 + ta;
      Ys[ta*136 + na] = f2b_u(d00[r] + b2f_u((u32)Xs[ta*136 + na]));
      Ys[ta*136 + nb] = f2b_u(d01[r] + b2f_u((u32)Xs[ta*136 + nb]));
      Ys[tb*136 + na] = f2b_u(d10[r] + b2f_u((u32)Xs[tb*136 + na]));
      Ys[tb*136 + nb] = f2b_u(d11[r] + b2f_u((u32)Xs[tb*136 + nb]));
    }
  }
  __syncthreads();

  // ---- coalesced store with layout mapping ----
  {
    int tok = t >> 3, oc = (t & 7)*16;
    uint4 v0 = *reinterpret_cast<const uint4*>(&Ys[tok*136 + oc]);
    uint4 v1 = *reinterpret_cast<const uint4*>(&Ys[tok*136 + oc + 8]);
    int T = bid*32 + tok;
    size_t addr;
    if (MODE == 1){
      int b = T >> 12, g = (T >> 4) & 255, ll = T & 15;
      addr = ((size_t)((b*16 + ll)*256 + g))*128 + oc;
    } else {
      int b = T >> 12, ll = (T >> 8) & 15, g = T & 255;
      int pcoord = ((g >> 4)*4 + (ll >> 2))*64 + ((g & 15)*4 + (ll & 3));
      addr = ((size_t)(b*4096 + pcoord))*128 + oc;
    }
    *reinterpret_cast<uint4*>(out + addr)     = v0;
    *reinterpret_cast<uint4*>(out + addr + 8) = v1;
  }
}

// ---------- K4a: QKV projection for DilatedMSA via MFMA ----------
__global__ __launch_bounds__(256) void k_qkv2(const u16* __restrict__ in, const u16* __restrict__ wB,
                                              const float* __restrict__ bias,
                                              u16* __restrict__ qbuf, u16* __restrict__ kvbuf){
  __shared__ u16 Xs[16*136];
  __shared__ u16 Qs[16*392];        // bf16 [tok][384+pad]
  int t = threadIdx.x, bid = blockIdx.x;
  {
    int l = t >> 4, c0 = (t & 15)*8;
    *reinterpret_cast<uint4*>(&Xs[l*136 + c0]) =
      *reinterpret_cast<const uint4*>(in + (size_t)bid*2048 + l*128 + c0);
  }
  __syncthreads();
  {
    int w = t >> 6, lane = t & 63, fr = lane & 15, fg = lane >> 4;
    bf16x8 a[4];
    #pragma unroll
    for (int k=0;k<4;k++) a[k] = *reinterpret_cast<const bf16x8*>(&Xs[fr*136 + k*32 + fg*8]);
    #pragma unroll
    for (int j=0;j<6;j++){
      int o = w*96 + j*16 + fr;          // 0..383
      float bv = bias[o];
      f32x4 d = {bv,bv,bv,bv};
      const u16* wp = wB + (size_t)o*128 + fg*8;
      #pragma unroll
      for (int k=0;k<4;k++){
        bf16x8 b = *reinterpret_cast<const bf16x8*>(wp + k*32);
        d = __builtin_amdgcn_mfma_f32_16x16x32_bf16(a[k], b, d, 0, 0, 0);
      }
      #pragma unroll
      for (int r=0;r<4;r++) Qs[(fg*4+r)*392 + o] = f2b_u(d[r]);
    }
  }
  __syncthreads();
  {
    int l = t >> 4, og = t & 15, o0 = og*24;
    size_t tok = (size_t)bid*16 + l;
    #pragma unroll
    for (int m=0; m<3; m++){
      int oc = o0 + m*8;
      uint4 v = *reinterpret_cast<const uint4*>(&Qs[l*392 + oc]);
      if (oc < 128) *reinterpret_cast<uint4*>(qbuf + tok*128 + oc) = v;
      else          *reinterpret_cast<uint4*>(kvbuf + tok*256 + (oc-128)) = v;
    }
  }
}

// ---------- K4b: DilatedMSA flash attention, full-MFMA (QK^T and PV), in-register softmax ----------
__global__ __launch_bounds__(256) void k_attn2(const u16* __restrict__ qbuf, const u16* __restrict__ kvbuf,
                                               u16* __restrict__ y){
  __shared__ __align__(16) char pool[24064];
  u16* Qb = (u16*)pool;              // [64][72] bf16
  u16* Kb = (u16*)(pool + 9216);     // [32][72] bf16
  u16* Vt = (u16*)(pool + 13824);    // [64 d][40 kt] bf16 (transposed V)
  u16* Pb = (u16*)(pool + 18944);    // [64 q][40 kt] bf16
  float* Os = (float*)pool;          // [64][68] f32, overlays Qb/Kb/Vt after loop

  int t = threadIdx.x, bid = blockIdx.x;
  int qt = bid & 3, h = (bid >> 2) & 1, bl = bid >> 3;
  size_t tokbase = (size_t)bl * 256;
  {
    int r = t >> 2, seg = t & 3;
    const u16* src = qbuf + (tokbase + qt*64 + r)*128 + h*64 + seg*16;
    uint4 v0 = *reinterpret_cast<const uint4*>(src);
    uint4 v1 = *reinterpret_cast<const uint4*>(src + 8);
    *reinterpret_cast<uint4*>(&Qb[r*72 + seg*16])     = v0;
    *reinterpret_cast<uint4*>(&Qb[r*72 + seg*16 + 8]) = v1;
  }
  int w = t >> 6, lane = t & 63;
  int fc = lane & 15, fg = lane >> 4;
  float m_reg[4], l_reg[4];
  #pragma unroll
  for (int r=0;r<4;r++){ m_reg[r] = -1e30f; l_reg[r] = 0.0f; }
  f32x4 o[4];
  #pragma unroll
  for (int j=0;j<4;j++) o[j] = {0.f,0.f,0.f,0.f};
  const float scale = 0.08838834764831845f;

  for (int kt=0; kt<8; kt++){
    {  // stage K rows (bf16)
      int r = t >> 3, seg = t & 7;
      const u16* base = kvbuf + (tokbase + kt*32 + r)*256 + h*64;
      *reinterpret_cast<uint4*>(&Kb[r*72 + seg*8]) = *reinterpret_cast<const uint4*>(base + seg*8);
    }
    {  // stage V transposed
      int pp = t >> 4, dg = t & 15, d0 = dg*4;
      const u16* b0 = kvbuf + (tokbase + kt*32 + 2*pp)*256 + h*64 + 128 + d0;
      uint2 v0 = *reinterpret_cast<const uint2*>(b0);
      uint2 v1 = *reinterpret_cast<const uint2*>(b0 + 256);
      *reinterpret_cast<u32*>(&Vt[(d0+0)*40 + 2*pp]) = (v0.x & 0xffffu) | (v1.x << 16);
      *reinterpret_cast<u32*>(&Vt[(d0+1)*40 + 2*pp]) = (v0.x >> 16) | (v1.x & 0xffff0000u);
      *reinterpret_cast<u32*>(&Vt[(d0+2)*40 + 2*pp]) = (v0.y & 0xffffu) | (v1.y << 16);
      *reinterpret_cast<u32*>(&Vt[(d0+3)*40 + 2*pp]) = (v0.y >> 16) | (v1.y & 0xffff0000u);
    }
    __syncthreads();
    f32x4 s0 = {0.f,0.f,0.f,0.f}, s1 = {0.f,0.f,0.f,0.f};
    {
      bf16x8 a0  = *reinterpret_cast<const bf16x8*>(&Qb[(w*16+fc)*72 + fg*8]);
      bf16x8 a1  = *reinterpret_cast<const bf16x8*>(&Qb[(w*16+fc)*72 + 32 + fg*8]);
      bf16x8 b00 = *reinterpret_cast<const bf16x8*>(&Kb[fc*72 + fg*8]);
      bf16x8 b01 = *reinterpret_cast<const bf16x8*>(&Kb[fc*72 + 32 + fg*8]);
      bf16x8 b10 = *reinterpret_cast<const bf16x8*>(&Kb[(16+fc)*72 + fg*8]);
      bf16x8 b11 = *reinterpret_cast<const bf16x8*>(&Kb[(16+fc)*72 + 32 + fg*8]);
      s0 = __builtin_amdgcn_mfma_f32_16x16x32_bf16(a0, b00, s0, 0, 0, 0);
      s0 = __builtin_amdgcn_mfma_f32_16x16x32_bf16(a1, b01, s0, 0, 0, 0);
      s1 = __builtin_amdgcn_mfma_f32_16x16x32_bf16(a0, b10, s1, 0, 0, 0);
      s1 = __builtin_amdgcn_mfma_f32_16x16x32_bf16(a1, b11, s1, 0, 0, 0);
    }
    float corr[4];
    #pragma unroll
    for (int r=0;r<4;r++){
      float v0 = s0[r]*scale, v1 = s1[r]*scale;
      float mx = fmaxf(v0, v1);
      mx = fmaxf(mx, __shfl_xor(mx, 1));
      mx = fmaxf(mx, __shfl_xor(mx, 2));
      mx = fmaxf(mx, __shfl_xor(mx, 4));
      mx = fmaxf(mx, __shfl_xor(mx, 8));
      float mnew = fmaxf(m_reg[r], mx);
      corr[r] = expf(m_reg[r] - mnew);
      m_reg[r] = mnew;
      float p0 = expf(v0 - mnew), p1 = expf(v1 - mnew);
      float sum = p0 + p1;
      sum += __shfl_xor(sum, 1);
      sum += __shfl_xor(sum, 2);
      sum += __shfl_xor(sum, 4);
      sum += __shfl_xor(sum, 8);
      l_reg[r] = l_reg[r]*corr[r] + sum;
      int row = w*16 + fg*4 + r;
      Pb[row*40 + fc]      = f2b_u(p0);
      Pb[row*40 + 16 + fc] = f2b_u(p1);
    }
    {
      bf16x8 pa = *reinterpret_cast<const bf16x8*>(&Pb[(w*16+fc)*40 + fg*8]);
      #pragma unroll
      for (int jt=0;jt<4;jt++){
        bf16x8 vb = *reinterpret_cast<const bf16x8*>(&Vt[(jt*16+fc)*40 + fg*8]);
        f32x4 oo = o[jt];
        oo[0] *= corr[0]; oo[1] *= corr[1]; oo[2] *= corr[2]; oo[3] *= corr[3];
        o[jt] = __builtin_amdgcn_mfma_f32_16x16x32_bf16(pa, vb, oo, 0, 0, 0);
      }
    }
    __syncthreads();
  }
  float inv[4];
  #pragma unroll
  for (int r=0;r<4;r++) inv[r] = 1.0f / l_reg[r];
  #pragma unroll
  for (int jt=0;jt<4;jt++){
    #pragma unroll
    for (int r=0;r<4;r++)
      Os[(w*16 + fg*4 + r)*68 + jt*16 + fc] = o[jt][r] * inv[r];
  }
  __syncthreads();
  {
    int row = t >> 2, seg = t & 3;
    float ov[16];
    #pragma unroll
    for (int j=0;j<16;j++) ov[j] = Os[row*68 + seg*16 + j];
    u16* dst = y + (tokbase + qt*64 + row)*128 + h*64 + seg*16;
    float res[16]; ld8b(dst, res); ld8b(dst+8, res+8);
    float o16[16];
    #pragma unroll
    for (int j=0;j<16;j++) o16[j] = ov[j] + res[j];
    st8b(dst, o16); st8b(dst+8, o16+8);
  }
}

// ---------- K6: FUSED LSTM (all 16 steps), 8 waves: K-split x/h + LDS combine ----------
// Waves 0-3: x-part (bias-seeded), gate = w. Waves 4-7: h-part (zero-seeded) -> partial LDS.
// Softmax/tanh, pointwise, IO keep the proven 256-thread code paths.
__global__ __launch_bounds__(512) void k_lstm_all(const u16* __restrict__ xD,
    const void* __restrict__ h0, const void* __restrict__ c0,
    const u16* __restrict__ wBx, const u16* __restrict__ wBh, const float* __restrict__ bh,
    void* __restrict__ dout, const int* __restrict__ flag){
  __shared__ u16 Xa[16*136];         // x bf16
  __shared__ u16 Ha[16*136];         // h bf16
  __shared__ float glds[4*16*132];   // [gate][px][132-pad ch] f32 (gate0 reused for hn f32)
  __shared__ float part[4*16*132];   // h-part partial sums f32
  __shared__ float Cls[16*132];      // C state f32
  __shared__ u16 hst[16*136];        // h-new bf16 staging
  int t = threadIdx.x, bid = blockIdx.x;
  int pix0 = bid*16;
  int fl = *flag;
  // ---- init h (bf16) and C (f32) from h0/c0 [c][4096] ----
  if (t < 256){
    int c = t >> 1, half = t & 1;
    int pxb = half*8;
    if (fl){
      const float* hp = (const float*)h0 + (size_t)c*4096 + pix0 + pxb;
      const float* cp = (const float*)c0 + (size_t)c*4096 + pix0 + pxb;
      #pragma unroll
      for (int i=0;i<8;i++){
        Ha[(pxb+i)*136 + c] = f2b_u(hp[i]);
        Cls[(pxb+i)*132 + c] = cp[i];
      }
    } else {
      const u16* hp = (const u16*)h0 + (size_t)c*4096 + pix0 + pxb;
      const u16* cp = (const u16*)c0 + (size_t)c*4096 + pix0 + pxb;
      #pragma unroll
      for (int i=0;i<8;i++){
        Ha[(pxb+i)*136 + c] = hp[i];
        Cls[(pxb+i)*132 + c] = b2f_u((u32)cp[i]);
      }
    }
  }
  int w = t >> 6, lane = t & 63, fr = lane & 15, fg = lane >> 4;
  int g = w & 3, ks = w >> 2;
  const u16* wSel = ks ? wBh : wBx;
  const u16* aSel = ks ? Ha : Xa;
  for (int n = 0; n < 16; n++){
    if (t < 256){ // load x tile
      int px = t >> 4, c0v = (t & 15)*8;
      *reinterpret_cast<uint4*>(&Xa[px*136 + c0v]) =
        *reinterpret_cast<const uint4*>(xD + ((size_t)n*4096 + pix0 + px)*128 + c0v);
    }
    __syncthreads();
    // gates GEMM: wave (g, ks): half-K over 128 channels of gate g
    f32x4 acc[8];
    {
      bf16x8 a[4];
      #pragma unroll
      for (int k=0;k<4;k++)
        a[k] = *reinterpret_cast<const bf16x8*>(&aSel[fr*136 + k*32 + fg*8]);
      #pragma unroll
      for (int j=0;j<8;j++){
        int o = g*128 + j*16 + fr;
        f32x4 d;
        if (ks == 0){ float bv = bh[o]; d = {bv,bv,bv,bv}; }
        else        { d = {0.f,0.f,0.f,0.f}; }
        const u16* wp = wSel + (size_t)o*128 + fg*8;
        #pragma unroll
        for (int k=0;k<4;k++){
          bf16x8 b = *reinterpret_cast<const bf16x8*>(wp + k*32);
          d = __builtin_amdgcn_mfma_f32_16x16x32_bf16(a[k], b, d, 0, 0, 0);
        }
        acc[j] = d;
      }
    }
    if (ks == 1){
      #pragma unroll
      for (int j=0;j<8;j++)
        #pragma unroll
        for (int r=0;r<4;r++)
          part[(g*16 + fg*4 + r)*132 + j*16 + fr] = acc[j][r];
    }
    __syncthreads();
    if (ks == 0){
      #pragma unroll
      for (int j=0;j<8;j++)
        #pragma unroll
        for (int r=0;r<4;r++)
          acc[j][r] += part[(g*16 + fg*4 + r)*132 + j*16 + fr];
      // activation: g==2 -> tanh; else channel-softmax (register butterfly over fc lanes)
      if (g == 2){
        #pragma unroll
        for (int j=0;j<8;j++)
          #pragma unroll
          for (int r=0;r<4;r++)
            glds[(g*16 + fg*4 + r)*132 + j*16 + fr] = tanhf(acc[j][r]);
      } else {
        #pragma unroll
        for (int r=0;r<4;r++){
          float mx = acc[0][r];
          #pragma unroll
          for (int j=1;j<8;j++) mx = fmaxf(mx, acc[j][r]);
          mx = fmaxf(mx, __shfl_xor(mx, 1));
          mx = fmaxf(mx, __shfl_xor(mx, 2));
          mx = fmaxf(mx, __shfl_xor(mx, 4));
          mx = fmaxf(mx, __shfl_xor(mx, 8));
          float e[8], sum = 0.f;
          #pragma unroll
          for (int j=0;j<8;j++){ e[j] = expf(acc[j][r] - mx); sum += e[j]; }
          sum += __shfl_xor(sum, 1);
          sum += __shfl_xor(sum, 2);
          sum += __shfl_xor(sum, 4);
          sum += __shfl_xor(sum, 8);
          float inv = 1.0f/sum;
          #pragma unroll
          for (int j=0;j<8;j++)
            glds[(g*16 + fg*4 + r)*132 + j*16 + fr] = e[j]*inv;
        }
      }
    }
    __syncthreads();
    // pointwise update: thread = (chg = t&15, px = t>>4); C in LDS
    if (t < 256){
      int chg = t & 15, px = t >> 4;
      int ch0 = chg*8;
      float fv[8], iv[8], sv[8], ov[8], cc[8];
      #pragma unroll
      for (int q2=0;q2<2;q2++){
        *reinterpret_cast<float4*>(&fv[q2*4]) = *reinterpret_cast<const float4*>(&glds[(0*16+px)*132 + ch0 + q2*4]);
        *reinterpret_cast<float4*>(&iv[q2*4]) = *reinterpret_cast<const float4*>(&glds[(1*16+px)*132 + ch0 + q2*4]);
        *reinterpret_cast<float4*>(&sv[q2*4]) = *reinterpret_cast<const float4*>(&glds[(2*16+px)*132 + ch0 + q2*4]);
        *reinterpret_cast<float4*>(&ov[q2*4]) = *reinterpret_cast<const float4*>(&glds[(3*16+px)*132 + ch0 + q2*4]);
        *reinterpret_cast<float4*>(&cc[q2*4]) = *reinterpret_cast<const float4*>(&Cls[px*132 + ch0 + q2*4]);
      }
      float cn[8], hn[8];
      #pragma unroll
      for (int j=0;j<8;j++){
        cn[j] = fv[j]*cc[j] + iv[j]*sv[j];
        hn[j] = ov[j]*tanhf(cn[j]);
      }
      #pragma unroll
      for (int q2=0;q2<2;q2++)
        *reinterpret_cast<float4*>(&Cls[px*132 + ch0 + q2*4]) = *reinterpret_cast<const float4*>(&cn[q2*4]);
      uint4 pk;
      pk.x = (u32)f2b_u(hn[0]) | ((u32)f2b_u(hn[1]) << 16);
      pk.y = (u32)f2b_u(hn[2]) | ((u32)f2b_u(hn[3]) << 16);
      pk.z = (u32)f2b_u(hn[4]) | ((u32)f2b_u(hn[5]) << 16);
      pk.w = (u32)f2b_u(hn[6]) | ((u32)f2b_u(hn[7]) << 16);
      *reinterpret_cast<uint4*>(&Ha[px*136 + ch0])  = pk;
      *reinterpret_cast<uint4*>(&hst[px*136 + ch0]) = pk;
      if (n == 15){
        // stash fp32 hn into glds gate-0 region (same cell this thread just read; no race)
        #pragma unroll
        for (int q2=0;q2<2;q2++)
          *reinterpret_cast<float4*>(&glds[px*132 + ch0 + q2*4]) = *reinterpret_cast<const float4*>(&hn[q2*4]);
      }
    }
    __syncthreads();
    // coalesced hs write (channel-major d_out)
    if (t < 256){
      int ch = t >> 1, ph = t & 1;
      size_t ob = (size_t)n*524288 + (size_t)ch*4096 + pix0 + ph*8;
      if (fl){
        float* df = (float*)dout;
        float v[8];
        #pragma unroll
        for (int i=0;i<8;i++) v[i] = b2f_u((u32)hst[(ph*8+i)*136 + ch]);
        *reinterpret_cast<float4*>(df + ob)     = make_float4(v[0],v[1],v[2],v[3]);
        *reinterpret_cast<float4*>(df + ob + 4) = make_float4(v[4],v[5],v[6],v[7]);
      } else {
        u16* db = (u16*)dout;
        uint4 pk;
        pk.x = (u32)hst[(ph*8+0)*136 + ch] | ((u32)hst[(ph*8+1)*136 + ch] << 16);
        pk.y = (u32)hst[(ph*8+2)*136 + ch] | ((u32)hst[(ph*8+3)*136 + ch] << 16);
        pk.z = (u32)hst[(ph*8+4)*136 + ch] | ((u32)hst[(ph*8+5)*136 + ch] << 16);
        pk.w = (u32)hst[(ph*8+6)*136 + ch] | ((u32)hst[(ph*8+7)*136 + ch] << 16);
        *reinterpret_cast<uint4*>(db + ob) = pk;
      }
    }
  }
  __syncthreads();
  // ---- final hf (fp32 from glds), Cf (fp32 from Cls) ----
  if (t < 256){
    int c = t >> 1, half = t & 1;
    int pxb = half*8;
    if (fl){
      float hv[8], cv[8];
      #pragma unroll
      for (int i=0;i<8;i++){ hv[i] = glds[(pxb+i)*132 + c]; cv[i] = Cls[(pxb+i)*132 + c]; }
      float* df = (float*)dout;
      size_t hb = 8388608u + (size_t)c*4096 + pix0 + pxb;
      size_t cb = 8912896u + (size_t)c*4096 + pix0 + pxb;
      *reinterpret_cast<float4*>(df + hb)     = make_float4(hv[0],hv[1],hv[2],hv[3]);
      *reinterpret_cast<float4*>(df + hb + 4) = make_float4(hv[4],hv[5],hv[6],hv[7]);
      *reinterpret_cast<float4*>(df + cb)     = make_float4(cv[0],cv[1],cv[2],cv[3]);
      *reinterpret_cast<float4*>(df + cb + 4) = make_float4(cv[4],cv[5],cv[6],cv[7]);
    } else {
      u16* db = (u16*)dout;
      uint4 hp, cp2;
      hp.x = (u32)hst[(pxb+0)*136 + c] | ((u32)hst[(pxb+1)*136 + c] << 16);
      hp.y = (u32)hst[(pxb+2)*136 + c] | ((u32)hst[(pxb+3)*136 + c] << 16);
      hp.z = (u32)hst[(pxb+4)*136 + c] | ((u32)hst[(pxb+5)*136 + c] << 16);
      hp.w = (u32)hst[(pxb+6)*136 + c] | ((u32)hst[(pxb+7)*136 + c] << 16);
      cp2.x = (u32)f2b_u(Cls[(pxb+0)*132 + c]) | ((u32)f2b_u(Cls[(pxb+1)*132 + c]) << 16);
      cp2.y = (u32)f2b_u(Cls[(pxb+2)*132 + c]) | ((u32)f2b_u(Cls[(pxb+3)*132 + c]) << 16);
      cp2.z = (u32)f2b_u(Cls[(pxb+4)*132 + c]) | ((u32)f2b_u(Cls[(pxb+5)*132 + c]) << 16);
      cp2.w = (u32)f2b_u(Cls[(pxb+6)*132 + c]) | ((u32)f2b_u(Cls[(pxb+7)*132 + c]) << 16);
      *reinterpret_cast<uint4*>(db + 8388608u + (size_t)c*4096 + pix0 + pxb) = hp;
      *reinterpret_cast<uint4*>(db + 8912896u + (size_t)c*4096 + pix0 + pxb) = cp2;
    }
  }
}

extern "C" void kernel_launch(void* const* d_in, const int* in_sizes, int n_in,
                              void* d_out, int out_size, void* d_ws, size_t ws_size,
                              hipStream_t stream) {
  const void* x      = d_in[0];
  const void* h0     = d_in[1];
  const void* c0     = d_in[2];
  const void* conv_w = d_in[3];
  const void* conv_b = d_in[4];
  const void* qkv1_w = d_in[5];
  const void* qkv1_b = d_in[6];
  const void* m1w1   = d_in[7];
  const void* m1b1   = d_in[8];
  const void* m1w2   = d_in[9];
  const void* m1b2   = d_in[10];
  const void* qkv2_w = d_in[11];
  const void* qkv2_b = d_in[12];
  const void* m2w1   = d_in[13];
  const void* m2b1   = d_in[14];
  const void* m2w2   = d_in[15];
  const void* m2b2   = d_in[16];
  const void* lwx    = d_in[17];
  const void* lwh    = d_in[18];
  const void* lbh    = d_in[19];

  char* p = (char*)d_ws;
  auto alloc = [&](size_t bytes)->void*{
    void* r = (void*)p; p += (bytes + 255) & ~(size_t)255; return r;
  };
  int*   flag    = (int*)alloc(256);
  u16* wB_conv = (u16*)alloc(128*512*2);       // bf16, native [co][ci*4+ky*2+kx]
  u16* wB_qkv1 = (u16*)alloc(384*128*2);       // bf16, original [o][k]
  u16* wB_m1a  = (u16*)alloc(512*128*2);
  u16* wB_m1b  = (u16*)alloc(128*512*2);
  u16* wB_qkv2 = (u16*)alloc(384*128*2);
  u16* wB_m2a  = (u16*)alloc(512*128*2);
  u16* wB_m2b  = (u16*)alloc(128*512*2);
  u16* wBx     = (u16*)alloc(512*128*2);       // bf16, original [o][k] (LSTM x)
  u16* wBh     = (u16*)alloc(512*128*2);       // bf16, original [o][k] (LSTM h)
  float* bf_conv = (float*)alloc(128*4);
  float* bf_qkv1 = (float*)alloc(384*4);
  float* bf_m1b1 = (float*)alloc(512*4);
  float* bf_m1b2 = (float*)alloc(128*4);
  float* bf_qkv2 = (float*)alloc(384*4);
  float* bf_m2b1 = (float*)alloc(512*4);
  float* bf_m2b2 = (float*)alloc(128*4);
  float* bf_lbh  = (float*)alloc(512*4);
  u16* R0   = (u16*)alloc(16777216);   // bufA -> bufC/y
  u16* Rbig = (u16*)alloc(33554432);   // bufB (front) -> kvbuf -> bufD (front)

  u16* bufA = R0;
  u16* bufB = Rbig;
  u16* bufC = R0;          // also y (attn writes in place)
  u16* qbuf = (u16*)d_out; // hs region used as scratch; dead before first LSTM write
  u16* kvbuf = Rbig;
  u16* bufD = Rbig;

  k_detect<<<1, 256, 0, stream>>>((const u32*)x, flag);

  k_prep<<<2187, 256, 0, stream>>>(
      conv_w, qkv1_w, m1w1, m1w2, qkv2_w, m2w1, m2w2, lwx, lwh,
      conv_b, qkv1_b, m1b1, m1b2, qkv2_b, m2b1, m2b2, lbh,
      wB_conv, wB_qkv1, wB_m1a, wB_m1b, wB_qkv2, wB_m2a, wB_m2b,
      wBx, wBh,
      bf_conv, bf_qkv1, bf_m1b1, bf_m1b2, bf_qkv2, bf_m2b1, bf_m2b2, bf_lbh,
      flag);

  k_conv<<<512, 256, 0, stream>>>(x, wB_conv, bf_conv, bufA, flag);
  k_msa1<<<4096, 256, 0, stream>>>(bufA, wB_qkv1, bf_qkv1, bufB);
  k_mlp<1><<<2048, 256, 0, stream>>>(bufB, wB_m1a, bf_m1b1, wB_m1b, bf_m1b2, bufC);
  k_qkv2<<<4096, 256, 0, stream>>>(bufC, wB_qkv2, bf_qkv2, qbuf, kvbuf);
  k_attn2<<<2048, 256, 0, stream>>>(qbuf, kvbuf, bufC);          // y = x + attn, in place
  k_mlp<2><<<2048, 256, 0, stream>>>(bufC, wB_m2a, bf_m2b1, wB_m2b, bf_m2b2, bufD);

  k_lstm_all<<<256, 512, 0, stream>>>(bufD, h0, c0, wBx, wBh, bf_lbh, d_out, flag);
}

// Round 17
// 645.470 us; speedup vs baseline: 1.1882x; 1.1882x over previous
//
#include <hip/hip_runtime.h>
#include <hip/hip_bf16.h>

typedef unsigned int u32;
typedef unsigned short u16;

#define DI __device__ __forceinline__

typedef __attribute__((ext_vector_type(8))) __bf16 bf16x8;
typedef __attribute__((ext_vector_type(4))) float f32x4;

// ---------- bf16 helpers (bf16 == fp32 high 16 bits; RNE on store) ----------
DI float b2f_u(u32 u){ return __uint_as_float(u << 16); }
DI u16 f2b_u(float f){
  u32 x = __float_as_uint(f);
  x += 0x7fffu + ((x >> 16) & 1u);
  return (u16)(x >> 16);
}
DI void ld8b(const u16* p, float* o){
  uint4 v = *reinterpret_cast<const uint4*>(p);
  o[0] = b2f_u(v.x & 0xffffu); o[1] = b2f_u(v.x >> 16);
  o[2] = b2f_u(v.y & 0xffffu); o[3] = b2f_u(v.y >> 16);
  o[4] = b2f_u(v.z & 0xffffu); o[5] = b2f_u(v.z >> 16);
  o[6] = b2f_u(v.w & 0xffffu); o[7] = b2f_u(v.w >> 16);
}
DI void st8b(u16* p, const float* i){
  uint4 v;
  v.x = (u32)f2b_u(i[0]) | ((u32)f2b_u(i[1]) << 16);
  v.y = (u32)f2b_u(i[2]) | ((u32)f2b_u(i[3]) << 16);
  v.z = (u32)f2b_u(i[4]) | ((u32)f2b_u(i[5]) << 16);
  v.w = (u32)f2b_u(i[6]) | ((u32)f2b_u(i[7]) << 16);
  *reinterpret_cast<uint4*>(p) = v;
}

// ---------- K_detect: is d_in fp32 (flag=1) or packed bf16 (flag=0)? ----------
__global__ void k_detect(const u32* __restrict__ xw, int* __restrict__ flag){
  __shared__ int cnt;
  int t = threadIdx.x;
  if (t == 0) cnt = 0;
  __syncthreads();
  int c = 0;
  for (int i = t; i < 2048; i += 256){
    u32 lo = xw[i] & 0xffffu;
    u32 e = (lo >> 7) & 0xffu;
    if (e < 100u || e > 140u) c++;
  }
  atomicAdd(&cnt, c);
  __syncthreads();
  if (t == 0) *flag = (cnt > 200) ? 1 : 0;
}

// ---------- K_prep: ALL weight/bias conversions in ONE launch ----------
__global__ void k_prep(
  const void* __restrict__ conv_w, const void* __restrict__ qkv1_w,
  const void* __restrict__ m1w1, const void* __restrict__ m1w2,
  const void* __restrict__ qkv2_w, const void* __restrict__ m2w1, const void* __restrict__ m2w2,
  const void* __restrict__ lwx, const void* __restrict__ lwh,
  const void* __restrict__ conv_b, const void* __restrict__ qkv1_b,
  const void* __restrict__ m1b1, const void* __restrict__ m1b2,
  const void* __restrict__ qkv2_b, const void* __restrict__ m2b1, const void* __restrict__ m2b2,
  const void* __restrict__ lbh,
  u16* __restrict__ wB_conv, u16* __restrict__ wB_qkv1, u16* __restrict__ wB_m1a,
  u16* __restrict__ wB_m1b, u16* __restrict__ wB_qkv2, u16* __restrict__ wB_m2a,
  u16* __restrict__ wB_m2b, u16* __restrict__ wBx, u16* __restrict__ wBh,
  float* __restrict__ bf_conv, float* __restrict__ bf_qkv1, float* __restrict__ bf_m1b1,
  float* __restrict__ bf_m1b2, float* __restrict__ bf_qkv2, float* __restrict__ bf_m2b1,
  float* __restrict__ bf_m2b2, float* __restrict__ bf_lbh,
  const int* __restrict__ flag){
  int bid = blockIdx.x, t = threadIdx.x;
  int fl = *flag;
  auto cvb = [&](const void* s, u16* d, int base, int n){
    int i = (bid - base)*256 + t;
    if (i < n) d[i] = fl ? f2b_u(((const float*)s)[i]) : ((const u16*)s)[i];
  };
  auto ldf = [&](const void* s, int i)->float{
    return fl ? ((const float*)s)[i] : b2f_u((u32)((const u16*)s)[i]);
  };
  if (bid < 256)       cvb(conv_w, wB_conv, 0,    65536);
  else if (bid < 448)  cvb(qkv1_w, wB_qkv1, 256,  49152);
  else if (bid < 704)  cvb(m1w1,   wB_m1a,  448,  65536);
  else if (bid < 960)  cvb(m1w2,   wB_m1b,  704,  65536);
  else if (bid < 1152) cvb(qkv2_w, wB_qkv2, 960,  49152);
  else if (bid < 1408) cvb(m2w1,   wB_m2a,  1152, 65536);
  else if (bid < 1664) cvb(m2w2,   wB_m2b,  1408, 65536);
  else if (bid < 1920) cvb(lwx,    wBx,     1664, 65536);
  else if (bid < 2176) cvb(lwh,    wBh,     1920, 65536);
  else {
    int i = (bid - 2176)*256 + t;
    if (i < 128)       bf_conv[i]        = ldf(conv_b, i);
    else if (i < 512)  bf_qkv1[i-128]    = ldf(qkv1_b, i-128);
    else if (i < 1024) bf_m1b1[i-512]    = ldf(m1b1,   i-512);
    else if (i < 1152) bf_m1b2[i-1024]   = ldf(m1b2,   i-1024);
    else if (i < 1536) bf_qkv2[i-1152]   = ldf(qkv2_b, i-1152);
    else if (i < 2048) bf_m2b1[i-1536]   = ldf(m2b1,   i-1536);
    else if (i < 2176) bf_m2b2[i-2048]   = ldf(m2b2,   i-2048);
    else if (i < 2688) bf_lbh[i-2176]    = ldf(lbh,    i-2176);
  }
}

// ---------- K1: conv 2x2 s2 + window partition via MFMA, strip-blocked ----------
__global__ __launch_bounds__(256) void k_conv(const void* __restrict__ x_raw,
                                              const u16* __restrict__ wB,
                                              const float* __restrict__ bias, u16* __restrict__ outA,
                                              const int* __restrict__ flag){
  __shared__ __align__(16) u16 pool[128*136];   // Aa [128][72] (first 18.4KB); Ys [128][136] overlay
  u16* Aa = pool;
  u16* Ys = pool;
  int t = threadIdx.x, bid = blockIdx.x;
  int xh = bid & 1, yg = (bid >> 1) & 15, b = bid >> 5;
  size_t slab = (size_t)b*2097152 + (size_t)(yg*8)*128 + (size_t)xh*64;
  int w = t >> 6, lane = t & 63, fr = lane & 15, fg = lane >> 4;
  f32x4 acc[2][8];
  #pragma unroll
  for (int j=0;j<8;j++){
    float bv = bias[j*16 + fr];
    acc[0][j] = {bv,bv,bv,bv};
    acc[1][j] = {bv,bv,bv,bv};
  }
  for (int ci0 = 0; ci0 < 128; ci0 += 16){
    if (ci0) __syncthreads();
    if (*flag){
      const float* xb = (const float*)x_raw + slab + (size_t)ci0*16384;
      #pragma unroll
      for (int i=0;i<4;i++){
        int idx = i*256 + t;            // 0..1023
        int row = idx >> 3, seg = idx & 7;   // row = cr*8+py (0..127), seg = 8-px group
        int cr = row >> 3, py = row & 7;
        const float* sp = xb + (size_t)cr*16384 + py*128 + seg*8;
        float4 v0 = *reinterpret_cast<const float4*>(sp);
        float4 v1 = *reinterpret_cast<const float4*>(sp + 4);
        int tok0 = seg*16 + (py>>1)*4;
        int k0 = cr*4 + (py&1)*2;
        *reinterpret_cast<u32*>(&Aa[(tok0+0)*72 + k0]) = (u32)f2b_u(v0.x) | ((u32)f2b_u(v0.y)<<16);
        *reinterpret_cast<u32*>(&Aa[(tok0+1)*72 + k0]) = (u32)f2b_u(v0.z) | ((u32)f2b_u(v0.w)<<16);
        *reinterpret_cast<u32*>(&Aa[(tok0+2)*72 + k0]) = (u32)f2b_u(v1.x) | ((u32)f2b_u(v1.y)<<16);
        *reinterpret_cast<u32*>(&Aa[(tok0+3)*72 + k0]) = (u32)f2b_u(v1.z) | ((u32)f2b_u(v1.w)<<16);
      }
    } else {
      const u16* xb = (const u16*)x_raw + slab + (size_t)ci0*16384;
      #pragma unroll
      for (int i=0;i<4;i++){
        int idx = i*256 + t;
        int row = idx >> 3, seg = idx & 7;
        int cr = row >> 3, py = row & 7;
        uint4 v = *reinterpret_cast<const uint4*>(xb + (size_t)cr*16384 + py*128 + seg*8);
        int tok0 = seg*16 + (py>>1)*4;
        int k0 = cr*4 + (py&1)*2;
        *reinterpret_cast<u32*>(&Aa[(tok0+0)*72 + k0]) = v.x;
        *reinterpret_cast<u32*>(&Aa[(tok0+1)*72 + k0]) = v.y;
        *reinterpret_cast<u32*>(&Aa[(tok0+2)*72 + k0]) = v.z;
        *reinterpret_cast<u32*>(&Aa[(tok0+3)*72 + k0]) = v.w;
      }
    }
    __syncthreads();
    bf16x8 a0[2], a1[2];
    #pragma unroll
    for (int kk=0;kk<2;kk++){
      a0[kk] = *reinterpret_cast<const bf16x8*>(&Aa[(w*16+fr)*72 + kk*32 + fg*8]);
      a1[kk] = *reinterpret_cast<const bf16x8*>(&Aa[((w+4)*16+fr)*72 + kk*32 + fg*8]);
    }
    #pragma unroll
    for (int j=0;j<8;j++){
      const u16* wp = wB + (size_t)(j*16+fr)*512 + ci0*4 + fg*8;
      bf16x8 b0 = *reinterpret_cast<const bf16x8*>(wp);
      bf16x8 b1 = *reinterpret_cast<const bf16x8*>(wp + 32);
      acc[0][j] = __builtin_amdgcn_mfma_f32_16x16x32_bf16(a0[0], b0, acc[0][j], 0, 0, 0);
      acc[0][j] = __builtin_amdgcn_mfma_f32_16x16x32_bf16(a0[1], b1, acc[0][j], 0, 0, 0);
      acc[1][j] = __builtin_amdgcn_mfma_f32_16x16x32_bf16(a1[0], b0, acc[1][j], 0, 0, 0);
      acc[1][j] = __builtin_amdgcn_mfma_f32_16x16x32_bf16(a1[1], b1, acc[1][j], 0, 0, 0);
    }
  }
  __syncthreads();
  #pragma unroll
  for (int tt=0;tt<2;tt++){
    int tokbase = (w + tt*4)*16;
    #pragma unroll
    for (int j=0;j<8;j++){
      #pragma unroll
      for (int r=0;r<4;r++)
        Ys[(tokbase + fg*4 + r)*136 + j*16 + fr] = f2b_u(acc[tt][j][r]);
    }
  }
  __syncthreads();
  {
    int tok = t >> 1, half = t & 1;
    int gl = yg*16 + xh*8 + (tok >> 4);
    int l = tok & 15;
    u16* dst = outA + ((size_t)(b*256 + gl)*16 + l)*128 + half*64;
    const u16* src = &Ys[tok*136 + half*64];
    #pragma unroll
    for (int q2=0;q2<8;q2++)
      *reinterpret_cast<uint4*>(dst + q2*8) = *reinterpret_cast<const uint4*>(src + q2*8);
  }
}

// ---------- K2: LocalMSA (L=16) + residual: bufA -> bufB (same layout) ----------
__global__ __launch_bounds__(256) void k_msa1(const u16* __restrict__ A, const u16* __restrict__ wB,
                                              const float* __restrict__ qbias, u16* __restrict__ B){
  __shared__ u16 Xs[16*136];        // bf16, row stride 272 B
  __shared__ float QKV[16*388];
  __shared__ float S[512];          // [h][l][m]
  int t = threadIdx.x, bid = blockIdx.x;
  {
    int l = t >> 4, c0 = (t & 15)*8;
    *reinterpret_cast<uint4*>(&Xs[l*136 + c0]) =
      *reinterpret_cast<const uint4*>(A + (size_t)bid*2048 + l*128 + c0);
  }
  __syncthreads();
  {
    int w = t >> 6, lane = t & 63, fr = lane & 15, fg = lane >> 4;
    bf16x8 a[4];
    #pragma unroll
    for (int k=0;k<4;k++) a[k] = *reinterpret_cast<const bf16x8*>(&Xs[fr*136 + k*32 + fg*8]);
    #pragma unroll
    for (int j=0;j<6;j++){
      int o = w*96 + j*16 + fr;          // 0..383
      float bv = qbias[o];
      f32x4 d = {bv,bv,bv,bv};
      const u16* wp = wB + (size_t)o*128 + fg*8;
      #pragma unroll
      for (int k=0;k<4;k++){
        bf16x8 b = *reinterpret_cast<const bf16x8*>(wp + k*32);
        d = __builtin_amdgcn_mfma_f32_16x16x32_bf16(a[k], b, d, 0, 0, 0);
      }
      #pragma unroll
      for (int r=0;r<4;r++) QKV[(fg*4+r)*388 + o] = d[r];
    }
  }
  __syncthreads();
  const float scale = 0.08838834764831845f;   // 1/sqrt(128)
  for (int e = t; e < 512; e += 256){
    int h = e >> 8, l = (e>>4)&15, m = e&15;
    const float* q = &QKV[l*388 + h*64];
    const float* kk = &QKV[m*388 + 128 + h*64];
    float s = 0.f;
    #pragma unroll
    for (int d=0; d<64; d++) s += q[d]*kk[d];
    S[(h*16+l)*16 + m] = s*scale;
  }
  __syncthreads();
  if (t < 32){
    float* row = &S[t*16];
    float mx = row[0];
    #pragma unroll
    for (int m=1;m<16;m++) mx = fmaxf(mx,row[m]);
    float sum = 0.f;
    #pragma unroll
    for (int m=0;m<16;m++){ float e = expf(row[m]-mx); row[m]=e; sum+=e; }
    float inv = 1.0f/sum;
    #pragma unroll
    for (int m=0;m<16;m++) row[m] *= inv;
  }
  __syncthreads();
  {
    int l = t >> 4, og = t & 15, o0 = og*8;
    int h = o0 >> 6;
    const float* p = &S[(h*16+l)*16];
    float out8[8];
    #pragma unroll
    for (int j=0;j<8;j++){
      int o = o0+j, d = o & 63;
      float s = 0.f;
      #pragma unroll
      for (int m=0;m<16;m++) s += p[m]*QKV[m*388 + 256 + h*64 + d];
      out8[j] = s + b2f_u((u32)Xs[l*136 + o]);
    }
    st8b(B + (size_t)bid*2048 + l*128 + o0, out8);
  }
}

// ---------- K3/K5: MLP (+residual) via MFMA, 32 tokens/block, H split in 2 passes ----------
// Hs holds one 256-channel half at a time (LDS 50.7 -> 34.3 KB => 4 blocks/CU).
// GEMM2 accumulators persist in registers across halves (k ascending) -> bit-identical.
template<int MODE>
__global__ __launch_bounds__(256) void k_mlp(const u16* __restrict__ in,
    const u16* __restrict__ w1B, const float* __restrict__ b1,
    const u16* __restrict__ w2B, const float* __restrict__ b2,
    u16* __restrict__ out){
  __shared__ u16 Xs[32*136];        // bf16 input (also residual), 8704 B
  __shared__ u16 Hs[32*264];        // bf16 hidden HALF, stride 264 (528 B rows, 16B-aligned), 16896 B
  __shared__ u16 Ys[32*136];        // bf16 output staging, 8704 B
  int t = threadIdx.x, bid = blockIdx.x;
  {
    int l = t >> 3, c0 = (t & 7)*16;
    const u16* src = in + (size_t)bid*4096 + l*128 + c0;
    *reinterpret_cast<uint4*>(&Xs[l*136 + c0])     = *reinterpret_cast<const uint4*>(src);
    *reinterpret_cast<uint4*>(&Xs[l*136 + c0 + 8]) = *reinterpret_cast<const uint4*>(src + 8);
  }
  __syncthreads();
  int w = t >> 6, lane = t & 63, fr = lane & 15, fg = lane >> 4;

  // X fragments (persist across both halves)
  bf16x8 a0[4], a1[4];
  #pragma unroll
  for (int k=0;k<4;k++){
    a0[k] = *reinterpret_cast<const bf16x8*>(&Xs[fr*136 + k*32 + fg*8]);
    a1[k] = *reinterpret_cast<const bf16x8*>(&Xs[(16+fr)*136 + k*32 + fg*8]);
  }

  // GEMM2 accumulators (persist across halves; k ascending -> same summation order)
  int na = w*32 + fr, nb = na + 16;   // 0..127
  float ba = b2[na], bb = b2[nb];
  f32x4 d00 = {ba,ba,ba,ba}, d01 = {bb,bb,bb,bb};
  f32x4 d10 = {ba,ba,ba,ba}, d11 = {bb,bb,bb,bb};
  const u16* wpa = w2B + (size_t)na*512 + fg*8;
  const u16* wpb = w2B + (size_t)nb*512 + fg*8;

  #pragma unroll
  for (int hh=0; hh<2; hh++){
    // ---- GEMM1 half: H[.., hh*256 .. +256) = gelu(X @ W1^T + b1); wave covers 64 ch ----
    #pragma unroll
    for (int j=0;j<4;j++){
      int o = hh*256 + w*64 + j*16 + fr;     // 0..511 across hh
      float bv = b1[o];
      f32x4 e0 = {bv,bv,bv,bv}, e1 = {bv,bv,bv,bv};
      const u16* wp = w1B + (size_t)o*128 + fg*8;
      #pragma unroll
      for (int k=0;k<4;k++){
        bf16x8 b = *reinterpret_cast<const bf16x8*>(wp + k*32);
        e0 = __builtin_amdgcn_mfma_f32_16x16x32_bf16(a0[k], b, e0, 0, 0, 0);
        e1 = __builtin_amdgcn_mfma_f32_16x16x32_bf16(a1[k], b, e1, 0, 0, 0);
      }
      int oc = o - hh*256;                   // 0..255 within half
      #pragma unroll
      for (int r=0;r<4;r++){
        float v0 = e0[r], v1 = e1[r];
        Hs[(fg*4+r)*264 + oc]      = f2b_u(0.5f*v0*(1.0f + erff(v0*0.70710678118654752f)));
        Hs[(16+fg*4+r)*264 + oc]   = f2b_u(0.5f*v1*(1.0f + erff(v1*0.70710678118654752f)));
      }
    }
    __syncthreads();
    // ---- GEMM2 partial: accumulate over this half's 256 channels ----
    #pragma unroll
    for (int k2=0;k2<8;k2++){
      int kg = hh*8 + k2;                    // global k-tile 0..15, ascending
      bf16x8 aa = *reinterpret_cast<const bf16x8*>(&Hs[fr*264 + k2*32 + fg*8]);
      bf16x8 ab = *reinterpret_cast<const bf16x8*>(&Hs[(16+fr)*264 + k2*32 + fg*8]);
      bf16x8 bA = *reinterpret_cast<const bf16x8*>(wpa + kg*32);
      bf16x8 bB = *reinterpret_cast<const bf16x8*>(wpb + kg*32);
      d00 = __builtin_amdgcn_mfma_f32_16x16x32_bf16(aa, bA, d00, 0, 0, 0);
      d01 = __builtin_amdgcn_mfma_f32_16x16x32_bf16(aa, bB, d01, 0, 0, 0);
      d10 = __builtin_amdgcn_mfma_f32_16x16x32_bf16(ab, bA, d10, 0, 0, 0);
      d11 = __builtin_amdgcn_mfma_f32_16x16x32_bf16(ab, bB, d11, 0, 0, 0);
    }
    __syncthreads();                          // Hs fully consumed before next half
  }

  // ---- epilogue: bias already seeded; add residual, stage, store ----
  #pragma unroll
  for (int r=0;r<4;r++){
    int ta = fg*4 + r, tb = 16 + ta;
    Ys[ta*136 + na] = f2b_u(d00[r] + b2f_u((u32)Xs[ta*136 + na]));
    Ys[ta*136 + nb] = f2b_u(d01[r] + b2f_u((u32)Xs[ta*136 + nb]));
    Ys[tb*136 + na] = f2b_u(d10[r] + b2f_u((u32)Xs[tb*136 + na]));
    Ys[tb*136 + nb] = f2b_u(d11[r] + b2f_u((u32)Xs[tb*136 + nb]));
  }
  __syncthreads();

  {
    int tok = t >> 3, oc = (t & 7)*16;
    uint4 v0 = *reinterpret_cast<const uint4*>(&Ys[tok*136 + oc]);
    uint4 v1 = *reinterpret_cast<const uint4*>(&Ys[tok*136 + oc + 8]);
    int T = bid*32 + tok;
    size_t addr;
    if (MODE == 1){
      int b = T >> 12, g = (T >> 4) & 255, ll = T & 15;
      addr = ((size_t)((b*16 + ll)*256 + g))*128 + oc;
    } else {
      int b = T >> 12, ll = (T >> 8) & 15, g = T & 255;
      int pcoord = ((g >> 4)*4 + (ll >> 2))*64 + ((g & 15)*4 + (ll & 3));
      addr = ((size_t)(b*4096 + pcoord))*128 + oc;
    }
    *reinterpret_cast<uint4*>(out + addr)     = v0;
    *reinterpret_cast<uint4*>(out + addr + 8) = v1;
  }
}

// ---------- K4a: QKV projection for DilatedMSA via MFMA ----------
__global__ __launch_bounds__(256) void k_qkv2(const u16* __restrict__ in, const u16* __restrict__ wB,
                                              const float* __restrict__ bias,
                                              u16* __restrict__ qbuf, u16* __restrict__ kvbuf){
  __shared__ u16 Xs[16*136];
  __shared__ u16 Qs[16*392];        // bf16 [tok][384+pad]
  int t = threadIdx.x, bid = blockIdx.x;
  {
    int l = t >> 4, c0 = (t & 15)*8;
    *reinterpret_cast<uint4*>(&Xs[l*136 + c0]) =
      *reinterpret_cast<const uint4*>(in + (size_t)bid*2048 + l*128 + c0);
  }
  __syncthreads();
  {
    int w = t >> 6, lane = t & 63, fr = lane & 15, fg = lane >> 4;
    bf16x8 a[4];
    #pragma unroll
    for (int k=0;k<4;k++) a[k] = *reinterpret_cast<const bf16x8*>(&Xs[fr*136 + k*32 + fg*8]);
    #pragma unroll
    for (int j=0;j<6;j++){
      int o = w*96 + j*16 + fr;          // 0..383
      float bv = bias[o];
      f32x4 d = {bv,bv,bv,bv};
      const u16* wp = wB + (size_t)o*128 + fg*8;
      #pragma unroll
      for (int k=0;k<4;k++){
        bf16x8 b = *reinterpret_cast<const bf16x8*>(wp + k*32);
        d = __builtin_amdgcn_mfma_f32_16x16x32_bf16(a[k], b, d, 0, 0, 0);
      }
      #pragma unroll
      for (int r=0;r<4;r++) Qs[(fg*4+r)*392 + o] = f2b_u(d[r]);
    }
  }
  __syncthreads();
  {
    int l = t >> 4, og = t & 15, o0 = og*24;
    size_t tok = (size_t)bid*16 + l;
    #pragma unroll
    for (int m=0; m<3; m++){
      int oc = o0 + m*8;
      uint4 v = *reinterpret_cast<const uint4*>(&Qs[l*392 + oc]);
      if (oc < 128) *reinterpret_cast<uint4*>(qbuf + tok*128 + oc) = v;
      else          *reinterpret_cast<uint4*>(kvbuf + tok*256 + (oc-128)) = v;
    }
  }
}

// ---------- K4b: DilatedMSA flash attention, full-MFMA (QK^T and PV), in-register softmax ----------
__global__ __launch_bounds__(256) void k_attn2(const u16* __restrict__ qbuf, const u16* __restrict__ kvbuf,
                                               u16* __restrict__ y){
  __shared__ __align__(16) char pool[24064];
  u16* Qb = (u16*)pool;              // [64][72] bf16
  u16* Kb = (u16*)(pool + 9216);     // [32][72] bf16
  u16* Vt = (u16*)(pool + 13824);    // [64 d][40 kt] bf16 (transposed V)
  u16* Pb = (u16*)(pool + 18944);    // [64 q][40 kt] bf16
  float* Os = (float*)pool;          // [64][68] f32, overlays Qb/Kb/Vt after loop

  int t = threadIdx.x, bid = blockIdx.x;
  int qt = bid & 3, h = (bid >> 2) & 1, bl = bid >> 3;
  size_t tokbase = (size_t)bl * 256;
  {
    int r = t >> 2, seg = t & 3;
    const u16* src = qbuf + (tokbase + qt*64 + r)*128 + h*64 + seg*16;
    uint4 v0 = *reinterpret_cast<const uint4*>(src);
    uint4 v1 = *reinterpret_cast<const uint4*>(src + 8);
    *reinterpret_cast<uint4*>(&Qb[r*72 + seg*16])     = v0;
    *reinterpret_cast<uint4*>(&Qb[r*72 + seg*16 + 8]) = v1;
  }
  int w = t >> 6, lane = t & 63;
  int fc = lane & 15, fg = lane >> 4;
  float m_reg[4], l_reg[4];
  #pragma unroll
  for (int r=0;r<4;r++){ m_reg[r] = -1e30f; l_reg[r] = 0.0f; }
  f32x4 o[4];
  #pragma unroll
  for (int j=0;j<4;j++) o[j] = {0.f,0.f,0.f,0.f};
  const float scale = 0.08838834764831845f;

  for (int kt=0; kt<8; kt++){
    {  // stage K rows (bf16)
      int r = t >> 3, seg = t & 7;
      const u16* base = kvbuf + (tokbase + kt*32 + r)*256 + h*64;
      *reinterpret_cast<uint4*>(&Kb[r*72 + seg*8]) = *reinterpret_cast<const uint4*>(base + seg*8);
    }
    {  // stage V transposed
      int pp = t >> 4, dg = t & 15, d0 = dg*4;
      const u16* b0 = kvbuf + (tokbase + kt*32 + 2*pp)*256 + h*64 + 128 + d0;
      uint2 v0 = *reinterpret_cast<const uint2*>(b0);
      uint2 v1 = *reinterpret_cast<const uint2*>(b0 + 256);
      *reinterpret_cast<u32*>(&Vt[(d0+0)*40 + 2*pp]) = (v0.x & 0xffffu) | (v1.x << 16);
      *reinterpret_cast<u32*>(&Vt[(d0+1)*40 + 2*pp]) = (v0.x >> 16) | (v1.x & 0xffff0000u);
      *reinterpret_cast<u32*>(&Vt[(d0+2)*40 + 2*pp]) = (v0.y & 0xffffu) | (v1.y << 16);
      *reinterpret_cast<u32*>(&Vt[(d0+3)*40 + 2*pp]) = (v0.y >> 16) | (v1.y & 0xffff0000u);
    }
    __syncthreads();
    f32x4 s0 = {0.f,0.f,0.f,0.f}, s1 = {0.f,0.f,0.f,0.f};
    {
      bf16x8 a0  = *reinterpret_cast<const bf16x8*>(&Qb[(w*16+fc)*72 + fg*8]);
      bf16x8 a1  = *reinterpret_cast<const bf16x8*>(&Qb[(w*16+fc)*72 + 32 + fg*8]);
      bf16x8 b00 = *reinterpret_cast<const bf16x8*>(&Kb[fc*72 + fg*8]);
      bf16x8 b01 = *reinterpret_cast<const bf16x8*>(&Kb[fc*72 + 32 + fg*8]);
      bf16x8 b10 = *reinterpret_cast<const bf16x8*>(&Kb[(16+fc)*72 + fg*8]);
      bf16x8 b11 = *reinterpret_cast<const bf16x8*>(&Kb[(16+fc)*72 + 32 + fg*8]);
      s0 = __builtin_amdgcn_mfma_f32_16x16x32_bf16(a0, b00, s0, 0, 0, 0);
      s0 = __builtin_amdgcn_mfma_f32_16x16x32_bf16(a1, b01, s0, 0, 0, 0);
      s1 = __builtin_amdgcn_mfma_f32_16x16x32_bf16(a0, b10, s1, 0, 0, 0);
      s1 = __builtin_amdgcn_mfma_f32_16x16x32_bf16(a1, b11, s1, 0, 0, 0);
    }
    float corr[4];
    #pragma unroll
    for (int r=0;r<4;r++){
      float v0 = s0[r]*scale, v1 = s1[r]*scale;
      float mx = fmaxf(v0, v1);
      mx = fmaxf(mx, __shfl_xor(mx, 1));
      mx = fmaxf(mx, __shfl_xor(mx, 2));
      mx = fmaxf(mx, __shfl_xor(mx, 4));
      mx = fmaxf(mx, __shfl_xor(mx, 8));
      float mnew = fmaxf(m_reg[r], mx);
      corr[r] = expf(m_reg[r] - mnew);
      m_reg[r] = mnew;
      float p0 = expf(v0 - mnew), p1 = expf(v1 - mnew);
      float sum = p0 + p1;
      sum += __shfl_xor(sum, 1);
      sum += __shfl_xor(sum, 2);
      sum += __shfl_xor(sum, 4);
      sum += __shfl_xor(sum, 8);
      l_reg[r] = l_reg[r]*corr[r] + sum;
      int row = w*16 + fg*4 + r;
      Pb[row*40 + fc]      = f2b_u(p0);
      Pb[row*40 + 16 + fc] = f2b_u(p1);
    }
    {
      bf16x8 pa = *reinterpret_cast<const bf16x8*>(&Pb[(w*16+fc)*40 + fg*8]);
      #pragma unroll
      for (int jt=0;jt<4;jt++){
        bf16x8 vb = *reinterpret_cast<const bf16x8*>(&Vt[(jt*16+fc)*40 + fg*8]);
        f32x4 oo = o[jt];
        oo[0] *= corr[0]; oo[1] *= corr[1]; oo[2] *= corr[2]; oo[3] *= corr[3];
        o[jt] = __builtin_amdgcn_mfma_f32_16x16x32_bf16(pa, vb, oo, 0, 0, 0);
      }
    }
    __syncthreads();
  }
  float inv[4];
  #pragma unroll
  for (int r=0;r<4;r++) inv[r] = 1.0f / l_reg[r];
  #pragma unroll
  for (int jt=0;jt<4;jt++){
    #pragma unroll
    for (int r=0;r<4;r++)
      Os[(w*16 + fg*4 + r)*68 + jt*16 + fc] = o[jt][r] * inv[r];
  }
  __syncthreads();
  {
    int row = t >> 2, seg = t & 3;
    float ov[16];
    #pragma unroll
    for (int j=0;j<16;j++) ov[j] = Os[row*68 + seg*16 + j];
    u16* dst = y + (tokbase + qt*64 + row)*128 + h*64 + seg*16;
    float res[16]; ld8b(dst, res); ld8b(dst+8, res+8);
    float o16[16];
    #pragma unroll
    for (int j=0;j<16;j++) o16[j] = ov[j] + res[j];
    st8b(dst, o16); st8b(dst+8, o16+8);
  }
}

// ---------- K6: FUSED LSTM (all 16 steps), 8 waves: K-split x/h + LDS combine ----------
__global__ __launch_bounds__(512) void k_lstm_all(const u16* __restrict__ xD,
    const void* __restrict__ h0, const void* __restrict__ c0,
    const u16* __restrict__ wBx, const u16* __restrict__ wBh, const float* __restrict__ bh,
    void* __restrict__ dout, const int* __restrict__ flag){
  __shared__ u16 Xa[16*136];         // x bf16
  __shared__ u16 Ha[16*136];         // h bf16
  __shared__ float glds[4*16*132];   // [gate][px][132-pad ch] f32 (gate0 reused for hn f32)
  __shared__ float part[4*16*132];   // h-part partial sums f32
  __shared__ float Cls[16*132];      // C state f32
  __shared__ u16 hst[16*136];        // h-new bf16 staging
  int t = threadIdx.x, bid = blockIdx.x;
  int pix0 = bid*16;
  int fl = *flag;
  if (t < 256){
    int c = t >> 1, half = t & 1;
    int pxb = half*8;
    if (fl){
      const float* hp = (const float*)h0 + (size_t)c*4096 + pix0 + pxb;
      const float* cp = (const float*)c0 + (size_t)c*4096 + pix0 + pxb;
      #pragma unroll
      for (int i=0;i<8;i++){
        Ha[(pxb+i)*136 + c] = f2b_u(hp[i]);
        Cls[(pxb+i)*132 + c] = cp[i];
      }
    } else {
      const u16* hp = (const u16*)h0 + (size_t)c*4096 + pix0 + pxb;
      const u16* cp = (const u16*)c0 + (size_t)c*4096 + pix0 + pxb;
      #pragma unroll
      for (int i=0;i<8;i++){
        Ha[(pxb+i)*136 + c] = hp[i];
        Cls[(pxb+i)*132 + c] = b2f_u((u32)cp[i]);
      }
    }
  }
  int w = t >> 6, lane = t & 63, fr = lane & 15, fg = lane >> 4;
  int g = w & 3, ks = w >> 2;
  const u16* wSel = ks ? wBh : wBx;
  const u16* aSel = ks ? Ha : Xa;
  for (int n = 0; n < 16; n++){
    if (t < 256){ // load x tile
      int px = t >> 4, c0v = (t & 15)*8;
      *reinterpret_cast<uint4*>(&Xa[px*136 + c0v]) =
        *reinterpret_cast<const uint4*>(xD + ((size_t)n*4096 + pix0 + px)*128 + c0v);
    }
    __syncthreads();
    f32x4 acc[8];
    {
      bf16x8 a[4];
      #pragma unroll
      for (int k=0;k<4;k++)
        a[k] = *reinterpret_cast<const bf16x8*>(&aSel[fr*136 + k*32 + fg*8]);
      #pragma unroll
      for (int j=0;j<8;j++){
        int o = g*128 + j*16 + fr;
        f32x4 d;
        if (ks == 0){ float bv = bh[o]; d = {bv,bv,bv,bv}; }
        else        { d = {0.f,0.f,0.f,0.f}; }
        const u16* wp = wSel + (size_t)o*128 + fg*8;
        #pragma unroll
        for (int k=0;k<4;k++){
          bf16x8 b = *reinterpret_cast<const bf16x8*>(wp + k*32);
          d = __builtin_amdgcn_mfma_f32_16x16x32_bf16(a[k], b, d, 0, 0, 0);
        }
        acc[j] = d;
      }
    }
    if (ks == 1){
      #pragma unroll
      for (int j=0;j<8;j++)
        #pragma unroll
        for (int r=0;r<4;r++)
          part[(g*16 + fg*4 + r)*132 + j*16 + fr] = acc[j][r];
    }
    __syncthreads();
    if (ks == 0){
      #pragma unroll
      for (int j=0;j<8;j++)
        #pragma unroll
        for (int r=0;r<4;r++)
          acc[j][r] += part[(g*16 + fg*4 + r)*132 + j*16 + fr];
      if (g == 2){
        #pragma unroll
        for (int j=0;j<8;j++)
          #pragma unroll
          for (int r=0;r<4;r++)
            glds[(g*16 + fg*4 + r)*132 + j*16 + fr] = tanhf(acc[j][r]);
      } else {
        #pragma unroll
        for (int r=0;r<4;r++){
          float mx = acc[0][r];
          #pragma unroll
          for (int j=1;j<8;j++) mx = fmaxf(mx, acc[j][r]);
          mx = fmaxf(mx, __shfl_xor(mx, 1));
          mx = fmaxf(mx, __shfl_xor(mx, 2));
          mx = fmaxf(mx, __shfl_xor(mx, 4));
          mx = fmaxf(mx, __shfl_xor(mx, 8));
          float e[8], sum = 0.f;
          #pragma unroll
          for (int j=0;j<8;j++){ e[j] = expf(acc[j][r] - mx); sum += e[j]; }
          sum += __shfl_xor(sum, 1);
          sum += __shfl_xor(sum, 2);
          sum += __shfl_xor(sum, 4);
          sum += __shfl_xor(sum, 8);
          float inv = 1.0f/sum;
          #pragma unroll
          for (int j=0;j<8;j++)
            glds[(g*16 + fg*4 + r)*132 + j*16 + fr] = e[j]*inv;
        }
      }
    }
    __syncthreads();
    if (t < 256){
      int chg = t & 15, px = t >> 4;
      int ch0 = chg*8;
      float fv[8], iv[8], sv[8], ov[8], cc[8];
      #pragma unroll
      for (int q2=0;q2<2;q2++){
        *reinterpret_cast<float4*>(&fv[q2*4]) = *reinterpret_cast<const float4*>(&glds[(0*16+px)*132 + ch0 + q2*4]);
        *reinterpret_cast<float4*>(&iv[q2*4]) = *reinterpret_cast<const float4*>(&glds[(1*16+px)*132 + ch0 + q2*4]);
        *reinterpret_cast<float4*>(&sv[q2*4]) = *reinterpret_cast<const float4*>(&glds[(2*16+px)*132 + ch0 + q2*4]);
        *reinterpret_cast<float4*>(&ov[q2*4]) = *reinterpret_cast<const float4*>(&glds[(3*16+px)*132 + ch0 + q2*4]);
        *reinterpret_cast<float4*>(&cc[q2*4]) = *reinterpret_cast<const float4*>(&Cls[px*132 + ch0 + q2*4]);
      }
      float cn[8], hn[8];
      #pragma unroll
      for (int j=0;j<8;j++){
        cn[j] = fv[j]*cc[j] + iv[j]*sv[j];
        hn[j] = ov[j]*tanhf(cn[j]);
      }
      #pragma unroll
      for (int q2=0;q2<2;q2++)
        *reinterpret_cast<float4*>(&Cls[px*132 + ch0 + q2*4]) = *reinterpret_cast<const float4*>(&cn[q2*4]);
      uint4 pk;
      pk.x = (u32)f2b_u(hn[0]) | ((u32)f2b_u(hn[1]) << 16);
      pk.y = (u32)f2b_u(hn[2]) | ((u32)f2b_u(hn[3]) << 16);
      pk.z = (u32)f2b_u(hn[4]) | ((u32)f2b_u(hn[5]) << 16);
      pk.w = (u32)f2b_u(hn[6]) | ((u32)f2b_u(hn[7]) << 16);
      *reinterpret_cast<uint4*>(&Ha[px*136 + ch0])  = pk;
      *reinterpret_cast<uint4*>(&hst[px*136 + ch0]) = pk;
      if (n == 15){
        #pragma unroll
        for (int q2=0;q2<2;q2++)
          *reinterpret_cast<float4*>(&glds[px*132 + ch0 + q2*4]) = *reinterpret_cast<const float4*>(&hn[q2*4]);
      }
    }
    __syncthreads();
    if (t < 256){
      int ch = t >> 1, ph = t & 1;
      size_t ob = (size_t)n*524288 + (size_t)ch*4096 + pix0 + ph*8;
      if (fl){
        float* df = (float*)dout;
        float v[8];
        #pragma unroll
        for (int i=0;i<8;i++) v[i] = b2f_u((u32)hst[(ph*8+i)*136 + ch]);
        *reinterpret_cast<float4*>(df + ob)     = make_float4(v[0],v[1],v[2],v[3]);
        *reinterpret_cast<float4*>(df + ob + 4) = make_float4(v[4],v[5],v[6],v[7]);
      } else {
        u16* db = (u16*)dout;
        uint4 pk;
        pk.x = (u32)hst[(ph*8+0)*136 + ch] | ((u32)hst[(ph*8+1)*136 + ch] << 16);
        pk.y = (u32)hst[(ph*8+2)*136 + ch] | ((u32)hst[(ph*8+3)*136 + ch] << 16);
        pk.z = (u32)hst[(ph*8+4)*136 + ch] | ((u32)hst[(ph*8+5)*136 + ch] << 16);
        pk.w = (u32)hst[(ph*8+6)*136 + ch] | ((u32)hst[(ph*8+7)*136 + ch] << 16);
        *reinterpret_cast<uint4*>(db + ob) = pk;
      }
    }
  }
  __syncthreads();
  if (t < 256){
    int c = t >> 1, half = t & 1;
    int pxb = half*8;
    if (fl){
      float hv[8], cv[8];
      #pragma unroll
      for (int i=0;i<8;i++){ hv[i] = glds[(pxb+i)*132 + c]; cv[i] = Cls[(pxb+i)*132 + c]; }
      float* df = (float*)dout;
      size_t hb = 8388608u + (size_t)c*4096 + pix0 + pxb;
      size_t cb = 8912896u + (size_t)c*4096 + pix0 + pxb;
      *reinterpret_cast<float4*>(df + hb)     = make_float4(hv[0],hv[1],hv[2],hv[3]);
      *reinterpret_cast<float4*>(df + hb + 4) = make_float4(hv[4],hv[5],hv[6],hv[7]);
      *reinterpret_cast<float4*>(df + cb)     = make_float4(cv[0],cv[1],cv[2],cv[3]);
      *reinterpret_cast<float4*>(df + cb + 4) = make_float4(cv[4],cv[5],cv[6],cv[7]);
    } else {
      u16* db = (u16*)dout;
      uint4 hp, cp2;
      hp.x = (u32)hst[(pxb+0)*136 + c] | ((u32)hst[(pxb+1)*136 + c] << 16);
      hp.y = (u32)hst[(pxb+2)*136 + c] | ((u32)hst[(pxb+3)*136 + c] << 16);
      hp.z = (u32)hst[(pxb+4)*136 + c] | ((u32)hst[(pxb+5)*136 + c] << 16);
      hp.w = (u32)hst[(pxb+6)*136 + c] | ((u32)hst[(pxb+7)*136 + c] << 16);
      cp2.x = (u32)f2b_u(Cls[(pxb+0)*132 + c]) | ((u32)f2b_u(Cls[(pxb+1)*132 + c]) << 16);
      cp2.y = (u32)f2b_u(Cls[(pxb+2)*132 + c]) | ((u32)f2b_u(Cls[(pxb+3)*132 + c]) << 16);
      cp2.z = (u32)f2b_u(Cls[(pxb+4)*132 + c]) | ((u32)f2b_u(Cls[(pxb+5)*132 + c]) << 16);
      cp2.w = (u32)f2b_u(Cls[(pxb+6)*132 + c]) | ((u32)f2b_u(Cls[(pxb+7)*132 + c]) << 16);
      *reinterpret_cast<uint4*>(db + 8388608u + (size_t)c*4096 + pix0 + pxb) = hp;
      *reinterpret_cast<uint4*>(db + 8912896u + (size_t)c*4096 + pix0 + pxb) = cp2;
    }
  }
}

extern "C" void kernel_launch(void* const* d_in, const int* in_sizes, int n_in,
                              void* d_out, int out_size, void* d_ws, size_t ws_size,
                              hipStream_t stream) {
  const void* x      = d_in[0];
  const void* h0     = d_in[1];
  const void* c0     = d_in[2];
  const void* conv_w = d_in[3];
  const void* conv_b = d_in[4];
  const void* qkv1_w = d_in[5];
  const void* qkv1_b = d_in[6];
  const void* m1w1   = d_in[7];
  const void* m1b1   = d_in[8];
  const void* m1w2   = d_in[9];
  const void* m1b2   = d_in[10];
  const void* qkv2_w = d_in[11];
  const void* qkv2_b = d_in[12];
  const void* m2w1   = d_in[13];
  const void* m2b1   = d_in[14];
  const void* m2w2   = d_in[15];
  const void* m2b2   = d_in[16];
  const void* lwx    = d_in[17];
  const void* lwh    = d_in[18];
  const void* lbh    = d_in[19];

  char* p = (char*)d_ws;
  auto alloc = [&](size_t bytes)->void*{
    void* r = (void*)p; p += (bytes + 255) & ~(size_t)255; return r;
  };
  int*   flag    = (int*)alloc(256);
  u16* wB_conv = (u16*)alloc(128*512*2);       // bf16, native [co][ci*4+ky*2+kx]
  u16* wB_qkv1 = (u16*)alloc(384*128*2);       // bf16, original [o][k]
  u16* wB_m1a  = (u16*)alloc(512*128*2);
  u16* wB_m1b  = (u16*)alloc(128*512*2);
  u16* wB_qkv2 = (u16*)alloc(384*128*2);
  u16* wB_m2a  = (u16*)alloc(512*128*2);
  u16* wB_m2b  = (u16*)alloc(128*512*2);
  u16* wBx     = (u16*)alloc(512*128*2);       // bf16, original [o][k] (LSTM x)
  u16* wBh     = (u16*)alloc(512*128*2);       // bf16, original [o][k] (LSTM h)
  float* bf_conv = (float*)alloc(128*4);
  float* bf_qkv1 = (float*)alloc(384*4);
  float* bf_m1b1 = (float*)alloc(512*4);
  float* bf_m1b2 = (float*)alloc(128*4);
  float* bf_qkv2 = (float*)alloc(384*4);
  float* bf_m2b1 = (float*)alloc(512*4);
  float* bf_m2b2 = (float*)alloc(128*4);
  float* bf_lbh  = (float*)alloc(512*4);
  u16* R0   = (u16*)alloc(16777216);   // bufA -> bufC/y
  u16* Rbig = (u16*)alloc(33554432);   // bufB (front) -> kvbuf -> bufD (front)

  u16* bufA = R0;
  u16* bufB = Rbig;
  u16* bufC = R0;          // also y (attn writes in place)
  u16* qbuf = (u16*)d_out; // hs region used as scratch; dead before first LSTM write
  u16* kvbuf = Rbig;
  u16* bufD = Rbig;

  k_detect<<<1, 256, 0, stream>>>((const u32*)x, flag);

  k_prep<<<2187, 256, 0, stream>>>(
      conv_w, qkv1_w, m1w1, m1w2, qkv2_w, m2w1, m2w2, lwx, lwh,
      conv_b, qkv1_b, m1b1, m1b2, qkv2_b, m2b1, m2b2, lbh,
      wB_conv, wB_qkv1, wB_m1a, wB_m1b, wB_qkv2, wB_m2a, wB_m2b,
      wBx, wBh,
      bf_conv, bf_qkv1, bf_m1b1, bf_m1b2, bf_qkv2, bf_m2b1, bf_m2b2, bf_lbh,
      flag);

  k_conv<<<512, 256, 0, stream>>>(x, wB_conv, bf_conv, bufA, flag);
  k_msa1<<<4096, 256, 0, stream>>>(bufA, wB_qkv1, bf_qkv1, bufB);
  k_mlp<1><<<2048, 256, 0, stream>>>(bufB, wB_m1a, bf_m1b1, wB_m1b, bf_m1b2, bufC);
  k_qkv2<<<4096, 256, 0, stream>>>(bufC, wB_qkv2, bf_qkv2, qbuf, kvbuf);
  k_attn2<<<2048, 256, 0, stream>>>(qbuf, kvbuf, bufC);          // y = x + attn, in place
  k_mlp<2><<<2048, 256, 0, stream>>>(bufC, wB_m2a, bf_m2b1, wB_m2b, bf_m2b2, bufD);

  k_lstm_all<<<256, 512, 0, stream>>>(bufD, h0, c0, wBx, wBh, bf_lbh, d_out, flag);
}